// Round 1
// baseline (263.534 us; speedup 1.0000x reference)
//
#include <hip/hip_runtime.h>

#define T_LEN 12
#define B_N   32768
#define H_N   128
#define E_N   64
#define K_N   192   // E + H
#define LDK   200   // padded LDS row stride (elements); 400B, 16B-aligned, bank-stride 4
#define BM    64    // batch rows per block

typedef __attribute__((ext_vector_type(8))) __bf16 bf16x8;
typedef __attribute__((ext_vector_type(8))) short  short8v;
typedef __attribute__((ext_vector_type(4))) float  f32x4;

__device__ __forceinline__ unsigned short f2bf(float f) {
  unsigned int u = __builtin_bit_cast(unsigned int, f);
  u += 0x7fffu + ((u >> 16) & 1u);          // round-to-nearest-even
  return (unsigned short)(u >> 16);
}
__device__ __forceinline__ float bf2f(unsigned short h) {
  unsigned int u = ((unsigned int)h) << 16;
  return __builtin_bit_cast(float, u);
}
__device__ __forceinline__ float sigm(float x) {
  return __builtin_amdgcn_rcpf(1.f + __builtin_amdgcn_exp2f(-1.4426950408889634f * x));
}
__device__ __forceinline__ float tanh_(float x) {
  // tanh(x) = 1 - 2/(e^{2x}+1)
  return 1.f - 2.f * __builtin_amdgcn_rcpf(__builtin_amdgcn_exp2f(2.8853900817779268f * x) + 1.f);
}

// Build combined bf16 weight matrix Wc[512][192] = [W_ih | W_hh], and b_lstm.
__global__ void prep_kernel(const float* __restrict__ Wih, const float* __restrict__ Whh,
                            const float* __restrict__ bih, const float* __restrict__ bhh,
                            unsigned short* __restrict__ Wc, float* __restrict__ bl) {
  int i = blockIdx.x * 256 + threadIdx.x;
  if (i < 4 * H_N) bl[i] = bih[i] + bhh[i];
  if (i < 4 * H_N * K_N) {
    int n = i / K_N, k = i - n * K_N;
    float v = (k < E_N) ? Wih[n * E_N + k] : Whh[n * H_N + (k - E_N)];
    Wc[i] = f2bf(v);
  }
}

// 8 waves = 512 threads. Block owns BM=64 batch rows for all T steps.
// Wave w owns hidden units [16w, 16w+16): gate columns {g*128 + 16w + (l&15)}.
// Weights live in registers (bw[4][6]) for the whole kernel.
__launch_bounds__(512, 2)
__global__ void decoder_kernel(const float* __restrict__ last_pos_rel,
                               const float* __restrict__ h0,
                               const float* __restrict__ c0,
                               const float* __restrict__ pps,
                               const float* __restrict__ W_se,
                               const float* __restrict__ b_se,
                               const float* __restrict__ W_hp,
                               const float* __restrict__ b_hp,
                               const unsigned short* __restrict__ Wc,
                               const float* __restrict__ bl,
                               float* __restrict__ out_rel,
                               float* __restrict__ out_h) {
  __shared__ unsigned short xh[BM * LDK];   // [row][k]: k 0..63 = x, 64..191 = h
  __shared__ float relbuf[BM * 2];
  __shared__ float whp[2 * H_N];

  const int tid  = threadIdx.x;
  const int w    = tid >> 6;
  const int l    = tid & 63;
  const int l15  = l & 15;
  const int lg   = l >> 4;
  const int brow = blockIdx.x * BM;
  const int nh   = w * 16 + l15;            // this lane's hidden-unit column

  // ---- persistent weight B-fragments: bw[gate][kstep], 8 contiguous k per lane ----
  short8v bw[4][6];
#pragma unroll
  for (int g = 0; g < 4; ++g)
#pragma unroll
    for (int ks = 0; ks < 6; ++ks)
      bw[g][ks] = *(const short8v*)(Wc + (g * H_N + nh) * K_N + ks * 32 + lg * 8);

  float bgate[4];
#pragma unroll
  for (int g = 0; g < 4; ++g) bgate[g] = bl[g * H_N + nh];

  // ---- c state in registers, C/D fragment layout: row = mt*16 + lg*4 + r, col = nh ----
  f32x4 cst[4];
#pragma unroll
  for (int mt = 0; mt < 4; ++mt)
#pragma unroll
    for (int r = 0; r < 4; ++r)
      cst[mt][r] = c0[(brow + mt * 16 + lg * 4 + r) * H_N + nh];

  // ---- stage constants / initial state ----
  if (tid < 2 * H_N) whp[tid] = W_hp[tid];
  for (int i = tid; i < BM * H_N; i += 512) {
    int row = i >> 7, n = i & (H_N - 1);
    xh[row * LDK + E_N + n] = f2bf(h0[(brow + row) * H_N + n]);
  }
  const int  xe   = tid & 63;
  const float wse0 = W_se[xe * 3 + 0], wse1 = W_se[xe * 3 + 1], wse2 = W_se[xe * 3 + 2];
  const float bse  = b_se[xe];
  const float bhp0 = b_hp[0], bhp1 = b_hp[1];

  // x0 = embed([last_pos_rel, speed_0])
#pragma unroll
  for (int rr = 0; rr < 8; ++rr) {
    int row = (tid >> 6) * 8 + rr;
    float r0 = last_pos_rel[(brow + row) * 2 + 0];
    float r1 = last_pos_rel[(brow + row) * 2 + 1];
    float sp = pps[0 * B_N + brow + row];
    xh[row * LDK + xe] = f2bf(r0 * wse0 + r1 * wse1 + sp * wse2 + bse);
  }

#pragma unroll 1
  for (int t = 0; t < T_LEN; ++t) {
    __syncthreads();   // xh (x and h) ready

    // ---- gates = xh @ Wc^T + b ----
    f32x4 acc[4][4];
#pragma unroll
    for (int g = 0; g < 4; ++g)
#pragma unroll
      for (int mt = 0; mt < 4; ++mt)
        acc[g][mt] = (f32x4){bgate[g], bgate[g], bgate[g], bgate[g]};

#pragma unroll
    for (int ks = 0; ks < 6; ++ks) {
      bf16x8 a[4];
#pragma unroll
      for (int mt = 0; mt < 4; ++mt)
        a[mt] = __builtin_bit_cast(bf16x8,
                 *(const short8v*)(xh + (mt * 16 + l15) * LDK + ks * 32 + lg * 8));
#pragma unroll
      for (int g = 0; g < 4; ++g)
#pragma unroll
        for (int mt = 0; mt < 4; ++mt)
          acc[g][mt] = __builtin_amdgcn_mfma_f32_16x16x32_bf16(
              a[mt], __builtin_bit_cast(bf16x8, bw[g][ks]), acc[g][mt], 0, 0, 0);
    }

    __syncthreads();   // all A-fragment reads done before h region is overwritten

    // ---- LSTM elementwise (lane-local) + h -> LDS ----
#pragma unroll
    for (int mt = 0; mt < 4; ++mt) {
#pragma unroll
      for (int r = 0; r < 4; ++r) {
        float gi = acc[0][mt][r], gf = acc[1][mt][r];
        float gg = acc[2][mt][r], go = acc[3][mt][r];
        float cn = sigm(gf) * cst[mt][r] + sigm(gi) * tanh_(gg);
        cst[mt][r] = cn;
        float h = sigm(go) * tanh_(cn);
        int row = mt * 16 + lg * 4 + r;
        xh[row * LDK + E_N + nh] = f2bf(h);
        if (t == T_LEN - 1) out_h[(brow + row) * H_N + nh] = h;
      }
    }

    __syncthreads();   // h ready

    // ---- rel = h @ W_hp^T + b_hp : 128 dots, 4 threads each ----
    {
      int dot = tid >> 2, part = tid & 3;
      int row = dot >> 1, j = dot & 1;
      float s = 0.f;
      int n0 = part * 32;
#pragma unroll
      for (int n = 0; n < 32; ++n)
        s += bf2f(xh[row * LDK + E_N + n0 + n]) * whp[j * H_N + n0 + n];
      s += __shfl_xor(s, 1);
      s += __shfl_xor(s, 2);
      if (part == 0) relbuf[dot] = s + (j ? bhp1 : bhp0);
    }

    __syncthreads();   // relbuf ready

    // ---- emit rels; x_{t+1} = embed([rel, speed_{t+1}]) ----
    if (tid < 2 * BM) out_rel[(size_t)t * B_N * 2 + brow * 2 + tid] = relbuf[tid];
    if (t < T_LEN - 1) {
#pragma unroll
      for (int rr = 0; rr < 8; ++rr) {
        int row = (tid >> 6) * 8 + rr;
        float r0 = relbuf[row * 2 + 0], r1 = relbuf[row * 2 + 1];
        float sp = pps[(t + 1) * B_N + brow + row];
        xh[row * LDK + xe] = f2bf(r0 * wse0 + r1 * wse1 + sp * wse2 + bse);
      }
    }
  }
}

extern "C" void kernel_launch(void* const* d_in, const int* in_sizes, int n_in,
                              void* d_out, int out_size, void* d_ws, size_t ws_size,
                              hipStream_t stream) {
  const float* last_pos_rel = (const float*)d_in[1];
  const float* h0   = (const float*)d_in[2];
  const float* c0   = (const float*)d_in[3];
  const float* pps  = (const float*)d_in[4];
  const float* W_se = (const float*)d_in[5];
  const float* b_se = (const float*)d_in[6];
  const float* W_ih = (const float*)d_in[7];
  const float* W_hh = (const float*)d_in[8];
  const float* b_ih = (const float*)d_in[9];
  const float* b_hh = (const float*)d_in[10];
  const float* W_hp = (const float*)d_in[11];
  const float* b_hp = (const float*)d_in[12];

  unsigned short* Wc = (unsigned short*)d_ws;
  float* bl = (float*)((char*)d_ws + (size_t)(4 * H_N) * K_N * sizeof(unsigned short));

  float* out_rel = (float*)d_out;
  float* out_h   = out_rel + (size_t)T_LEN * B_N * 2;

  hipLaunchKernelGGL(prep_kernel, dim3((4 * H_N * K_N + 255) / 256), dim3(256), 0, stream,
                     W_ih, W_hh, b_ih, b_hh, Wc, bl);
  hipLaunchKernelGGL(decoder_kernel, dim3(B_N / BM), dim3(512), 0, stream,
                     last_pos_rel, h0, c0, pps, W_se, b_se, W_hp, b_hp, Wc, bl,
                     out_rel, out_h);
}

// Round 2
// 261.800 us; speedup vs baseline: 1.0066x; 1.0066x over previous
//
#include <hip/hip_runtime.h>

#define T_LEN 12
#define B_N   32768
#define H_N   128
#define E_N   64
#define BM    32    // batch rows per block

typedef __attribute__((ext_vector_type(8))) __bf16 bf16x8;
typedef __attribute__((ext_vector_type(8))) short  short8v;
typedef __attribute__((ext_vector_type(4))) float  f32x4;

__device__ __forceinline__ unsigned short f2bf(float f) {
  unsigned int u = __builtin_bit_cast(unsigned int, f);
  u += 0x7fffu + ((u >> 16) & 1u);
  return (unsigned short)(u >> 16);
}
__device__ __forceinline__ float sigm(float x) {
  return __builtin_amdgcn_rcpf(1.f + __builtin_amdgcn_exp2f(-1.4426950408889634f * x));
}
__device__ __forceinline__ float tanh_(float x) {
  return 1.f - 2.f * __builtin_amdgcn_rcpf(__builtin_amdgcn_exp2f(2.8853900817779268f * x) + 1.f);
}

// Precompute fused weights:
//   Wf[512][128] = Whh + (Wih@Wse01)@Whp      (bf16)
//   G[512][2]    = Wih@Wse01                  (f32)
//   u[512]       = Wih@wse2                   (f32)
//   w0[512]      = bih+bhh+Wih@bse+G@bhp      (f32)
__global__ void prep_kernel(const float* __restrict__ Wih, const float* __restrict__ Whh,
                            const float* __restrict__ bih, const float* __restrict__ bhh,
                            const float* __restrict__ Wse, const float* __restrict__ bse,
                            const float* __restrict__ Whp, const float* __restrict__ bhp,
                            unsigned short* __restrict__ Wf, float* __restrict__ u,
                            float* __restrict__ w0, float* __restrict__ G) {
  int i = blockIdx.x * 256 + threadIdx.x;
  if (i < 512 * 128) {
    int n = i >> 7, k = i & 127;
    float s = Whh[n * 128 + k];
    float wh0 = Whp[k], wh1 = Whp[128 + k];
    for (int e = 0; e < 64; ++e)
      s += Wih[n * 64 + e] * (Wse[e * 3 + 0] * wh0 + Wse[e * 3 + 1] * wh1);
    Wf[i] = f2bf(s);
  } else if (i < 512 * 128 + 2048) {
    int j = i - 512 * 128;
    int n = j >> 2, which = j & 3;
    float s = 0.f;
    if (which < 2) {
      for (int e = 0; e < 64; ++e) s += Wih[n * 64 + e] * Wse[e * 3 + which];
      G[n * 2 + which] = s;
    } else if (which == 2) {
      for (int e = 0; e < 64; ++e) s += Wih[n * 64 + e] * Wse[e * 3 + 2];
      u[n] = s;
    } else {
      for (int e = 0; e < 64; ++e)
        s += Wih[n * 64 + e] * (bse[e] + Wse[e * 3 + 0] * bhp[0] + Wse[e * 3 + 1] * bhp[1]);
      w0[n] = bih[n] + bhh[n] + s;
    }
  }
}

// 8 waves, BM=32 rows/block, grid 1024. Two phases / two barriers per step.
// Wave w owns gate columns {g*128 + w*16 + (l&15)} for g=0..3.
// Gates i,f weights in registers (32 VGPR); gates g,o weights in swizzled LDS.
__launch_bounds__(512, 4)
__global__ void decoder_kernel(const float* __restrict__ lpr,
                               const float* __restrict__ h0,
                               const float* __restrict__ c0,
                               const float* __restrict__ pps,
                               const float* __restrict__ Whp,
                               const float* __restrict__ bhp,
                               const unsigned short* __restrict__ Wf,
                               const float* __restrict__ u,
                               const float* __restrict__ w0,
                               const float* __restrict__ G,
                               float* __restrict__ out_rel,
                               float* __restrict__ out_h) {
  __shared__ unsigned short WfL[256 * 128];   // gates g,o weights, XOR-swizzled, 64KB
  __shared__ unsigned short hS[BM * 128];     // h (bf16), XOR-swizzled, 8KB
  __shared__ unsigned short whpB[4 * 64 * 8]; // W_hp B-frags per kstep, 4KB
  __shared__ float spdbuf[BM];
  __shared__ float dbuf[BM * 2];              // step-0 delta

  const int tid  = threadIdx.x;
  const int w    = tid >> 6;
  const int l    = tid & 63;
  const int l15  = l & 15;
  const int lg   = l >> 4;
  const int brow = blockIdx.x * BM;
  const int nh   = w * 16 + l15;
  const int swz  = (l15 & 7) << 4;
  char* hB  = (char*)hS;
  char* wB  = (char*)WfL;
  char* pB  = (char*)whpB;

  // ---- stage WfL (gates 2,3): global rows 256..511 -> swizzled LDS ----
  for (int i = tid; i < 256 * 16; i += 512) {      // 16B chunks
    int row = i >> 4, k16 = i & 15;
    short8v v = *(const short8v*)(Wf + (256 + row) * 128 + k16 * 8);
    int byte = (row * 256 + k16 * 16) ^ ((row & 7) << 4);
    *(short8v*)(wB + byte) = v;
  }
  // ---- persistent weights gates 0,1 (i,f) ----
  short8v bw[2][4];
#pragma unroll
  for (int g = 0; g < 2; ++g)
#pragma unroll
    for (int ks = 0; ks < 4; ++ks)
      bw[g][ks] = *(const short8v*)(Wf + (g * 128 + nh) * 128 + ks * 32 + lg * 8);

  float ur[4], w0r[4];
#pragma unroll
  for (int g = 0; g < 4; ++g) { ur[g] = u[g * 128 + nh]; w0r[g] = w0[g * 128 + nh]; }

  // ---- c state: C/D layout row = mt*16 + lg*4 + r, col = nh ----
  f32x4 cst[2];
#pragma unroll
  for (int mt = 0; mt < 2; ++mt)
#pragma unroll
    for (int r = 0; r < 4; ++r)
      cst[mt][r] = c0[(brow + mt * 16 + lg * 4 + r) * H_N + nh];

  // ---- h0 -> swizzled LDS bf16 ----
  {
    int row = tid >> 4, k0 = (tid & 15) * 8;
    const float* src = h0 + (brow + row) * H_N + k0;
    unsigned short tmp[8];
#pragma unroll
    for (int j = 0; j < 8; ++j) tmp[j] = f2bf(src[j]);
    int byte = (row * 256 + k0 * 2) ^ ((row & 7) << 4);
    *(short8v*)(hB + byte) = *(short8v*)tmp;
  }
  // ---- whpB: B-frags of W_hp (cols 0,1 real, 2..15 zero) ----
  if (tid < 256) {
    int ks = tid >> 6, ll = tid & 63, c = ll & 15, kg = ll >> 4;
    unsigned short tmp[8];
#pragma unroll
    for (int j = 0; j < 8; ++j)
      tmp[j] = (c < 2) ? f2bf(Whp[c * 128 + ks * 32 + kg * 8 + j]) : (unsigned short)0;
    *(short8v*)(pB + (ks * 64 + ll) * 16) = *(short8v*)tmp;
  }
  // ---- delta = lpr - h0@Whp^T - bhp  (fp32, 8 threads per dot) ----
  {
    int dot = tid >> 3, part = tid & 7;   // dot = row*2 + j
    int row = dot >> 1, j = dot & 1;
    float s = 0.f;
    const float* hrow = h0 + (brow + row) * H_N + part * 16;
    const float* wrow = Whp + j * 128 + part * 16;
#pragma unroll
    for (int k = 0; k < 16; ++k) s += hrow[k] * wrow[k];
    s += __shfl_xor(s, 1); s += __shfl_xor(s, 2); s += __shfl_xor(s, 4);
    if (part == 0) dbuf[dot] = lpr[(brow + row) * 2 + j] - bhp[j] - s;
  }
  const float bhpr = (l15 < 2) ? bhp[l15] : 0.f;

#pragma unroll 1
  for (int t = 0; t < T_LEN; ++t) {
    __syncthreads();   // h_{t-1} (or init) ready

    // ================= phase A: MFMA =================
    if (tid < BM) spdbuf[tid] = pps[t * B_N + brow + tid];

    f32x4 acc[4][2];
#pragma unroll
    for (int g = 0; g < 4; ++g)
#pragma unroll
      for (int mt = 0; mt < 2; ++mt) acc[g][mt] = (f32x4){0.f, 0.f, 0.f, 0.f};
    f32x4 relC = (f32x4){0.f, 0.f, 0.f, 0.f};

#pragma unroll
    for (int ks = 0; ks < 4; ++ks) {
      int kb = ks * 64 + lg * 16;
      bf16x8 a0 = __builtin_bit_cast(bf16x8, *(short8v*)(hB + ((l15 * 256 + kb) ^ swz)));
      bf16x8 a1 = __builtin_bit_cast(bf16x8, *(short8v*)(hB + (((16 + l15) * 256 + kb) ^ swz)));
      bf16x8 b2 = __builtin_bit_cast(bf16x8, *(short8v*)(wB + ((nh * 256 + kb) ^ swz)));
      bf16x8 b3 = __builtin_bit_cast(bf16x8, *(short8v*)(wB + 32768 + ((nh * 256 + kb) ^ swz)));
      acc[0][0] = __builtin_amdgcn_mfma_f32_16x16x32_bf16(a0, __builtin_bit_cast(bf16x8, bw[0][ks]), acc[0][0], 0, 0, 0);
      acc[0][1] = __builtin_amdgcn_mfma_f32_16x16x32_bf16(a1, __builtin_bit_cast(bf16x8, bw[0][ks]), acc[0][1], 0, 0, 0);
      acc[1][0] = __builtin_amdgcn_mfma_f32_16x16x32_bf16(a0, __builtin_bit_cast(bf16x8, bw[1][ks]), acc[1][0], 0, 0, 0);
      acc[1][1] = __builtin_amdgcn_mfma_f32_16x16x32_bf16(a1, __builtin_bit_cast(bf16x8, bw[1][ks]), acc[1][1], 0, 0, 0);
      acc[2][0] = __builtin_amdgcn_mfma_f32_16x16x32_bf16(a0, b2, acc[2][0], 0, 0, 0);
      acc[2][1] = __builtin_amdgcn_mfma_f32_16x16x32_bf16(a1, b2, acc[2][1], 0, 0, 0);
      acc[3][0] = __builtin_amdgcn_mfma_f32_16x16x32_bf16(a0, b3, acc[3][0], 0, 0, 0);
      acc[3][1] = __builtin_amdgcn_mfma_f32_16x16x32_bf16(a1, b3, acc[3][1], 0, 0, 0);
      if (w < 2 && t > 0) {
        bf16x8 wb = __builtin_bit_cast(bf16x8, *(short8v*)(pB + ks * 1024 + l * 16));
        relC = __builtin_amdgcn_mfma_f32_16x16x32_bf16(w == 0 ? a0 : a1, wb, relC, 0, 0, 0);
      }
    }
    if (w < 2 && t > 0 && l15 < 2) {
#pragma unroll
      for (int r = 0; r < 4; ++r)
        out_rel[(size_t)(t - 1) * B_N * 2 + (brow + w * 16 + lg * 4 + r) * 2 + l15] = relC[r] + bhpr;
    }

    __syncthreads();   // all reads of h_{t-1} done

    // ================= phase B: elementwise =================
#pragma unroll
    for (int mt = 0; mt < 2; ++mt) {
#pragma unroll
      for (int r = 0; r < 4; ++r) {
        int row = mt * 16 + lg * 4 + r;
        float spd = spdbuf[row];
        float gi = acc[0][mt][r] + w0r[0] + spd * ur[0];
        float gf = acc[1][mt][r] + w0r[1] + spd * ur[1];
        float gg = acc[2][mt][r] + w0r[2] + spd * ur[2];
        float go = acc[3][mt][r] + w0r[3] + spd * ur[3];
        if (t == 0) {
          float d0 = dbuf[row * 2 + 0], d1 = dbuf[row * 2 + 1];
          gi += d0 * G[(0 * 128 + nh) * 2 + 0] + d1 * G[(0 * 128 + nh) * 2 + 1];
          gf += d0 * G[(1 * 128 + nh) * 2 + 0] + d1 * G[(1 * 128 + nh) * 2 + 1];
          gg += d0 * G[(2 * 128 + nh) * 2 + 0] + d1 * G[(2 * 128 + nh) * 2 + 1];
          go += d0 * G[(3 * 128 + nh) * 2 + 0] + d1 * G[(3 * 128 + nh) * 2 + 1];
        }
        float cn = sigm(gf) * cst[mt][r] + sigm(gi) * tanh_(gg);
        cst[mt][r] = cn;
        float h = sigm(go) * tanh_(cn);
        hS[((row * 256 + nh * 2) ^ ((row & 7) << 4)) >> 1] = f2bf(h);
        if (t == T_LEN - 1) out_h[(brow + row) * H_N + nh] = h;
      }
    }
  }

  __syncthreads();   // h_11 ready
  // ---- epilogue: rel_11 ----
  if (w < 2) {
    f32x4 relC = (f32x4){0.f, 0.f, 0.f, 0.f};
#pragma unroll
    for (int ks = 0; ks < 4; ++ks) {
      int kb = ks * 64 + lg * 16;
      bf16x8 a = __builtin_bit_cast(bf16x8,
          *(short8v*)(hB + (((w * 16 + l15) * 256 + kb) ^ swz)));
      bf16x8 wb = __builtin_bit_cast(bf16x8, *(short8v*)(pB + ks * 1024 + l * 16));
      relC = __builtin_amdgcn_mfma_f32_16x16x32_bf16(a, wb, relC, 0, 0, 0);
    }
    if (l15 < 2) {
#pragma unroll
      for (int r = 0; r < 4; ++r)
        out_rel[(size_t)(T_LEN - 1) * B_N * 2 + (brow + w * 16 + lg * 4 + r) * 2 + l15] = relC[r] + bhpr;
    }
  }
}

extern "C" void kernel_launch(void* const* d_in, const int* in_sizes, int n_in,
                              void* d_out, int out_size, void* d_ws, size_t ws_size,
                              hipStream_t stream) {
  const float* lpr  = (const float*)d_in[1];
  const float* h0   = (const float*)d_in[2];
  const float* c0   = (const float*)d_in[3];
  const float* pps  = (const float*)d_in[4];
  const float* W_se = (const float*)d_in[5];
  const float* b_se = (const float*)d_in[6];
  const float* W_ih = (const float*)d_in[7];
  const float* W_hh = (const float*)d_in[8];
  const float* b_ih = (const float*)d_in[9];
  const float* b_hh = (const float*)d_in[10];
  const float* W_hp = (const float*)d_in[11];
  const float* b_hp = (const float*)d_in[12];

  unsigned short* Wf = (unsigned short*)d_ws;                    // 128KB
  float* u  = (float*)((char*)d_ws + 131072);                    // 2KB
  float* w0 = (float*)((char*)d_ws + 133120);                    // 2KB
  float* G  = (float*)((char*)d_ws + 135168);                    // 4KB

  float* out_rel = (float*)d_out;
  float* out_h   = out_rel + (size_t)T_LEN * B_N * 2;

  hipLaunchKernelGGL(prep_kernel, dim3((512 * 128 + 2048 + 255) / 256), dim3(256), 0, stream,
                     W_ih, W_hh, b_ih, b_hh, W_se, b_se, W_hp, b_hp, Wf, u, w0, G);
  hipLaunchKernelGGL(decoder_kernel, dim3(B_N / BM), dim3(512), 0, stream,
                     lpr, h0, c0, pps, W_hp, b_hp, Wf, u, w0, G, out_rel, out_h);
}